// Round 2
// baseline (854.436 us; speedup 1.0000x reference)
//
#include <hip/hip_runtime.h>
#include <hip/hip_bf16.h>

#define M_ROWS 12000
#define K_DIM  12000
#define FEAT   256
#define NCLS   40
#define STEPS_TOTAL 375   // 12000 / 32

typedef __attribute__((ext_vector_type(4))) float f32x4;
typedef __attribute__((ext_vector_type(8))) short s16x8;
typedef __attribute__((ext_vector_type(4))) short s16x4;

__device__ __forceinline__ short f2bf(float f){
  __hip_bfloat16 h = __float2bfloat16(f);
  union { __hip_bfloat16 h; short s; } u; u.h = h; return u.s;
}

__device__ __forceinline__ f32x4 mfma16(s16x8 a, s16x8 b, f32x4 c){
  return __builtin_amdgcn_mfma_f32_16x16x32_bf16(a, b, c, 0, 0, 0);
}

// ---------------------------------------------------------------------------
// fp32 [12000][256]  ->  bf16 [256][12000]  (transposed; used once, for x)
// ---------------------------------------------------------------------------
__global__ __launch_bounds__(256) void k_transpose_bf16(const float* __restrict__ src,
                                                        short* __restrict__ dst){
  __shared__ float tile[32][257];
  const int t  = threadIdx.x;
  const int r0 = blockIdx.x * 32;
  {
    const int r = t >> 3, cs = (t & 7) * 32;
    const float* s = src + (size_t)(r0 + r) * FEAT + cs;
    #pragma unroll
    for (int i = 0; i < 8; ++i){
      f32x4 v = *(const f32x4*)(s + 4*i);
      tile[r][cs + 4*i + 0] = v[0];
      tile[r][cs + 4*i + 1] = v[1];
      tile[r][cs + 4*i + 2] = v[2];
      tile[r][cs + 4*i + 3] = v[3];
    }
  }
  __syncthreads();
  const int c = t;
  short* d = dst + (size_t)c * M_ROWS + r0;
  #pragma unroll
  for (int i = 0; i < 4; ++i){
    s16x8 o;
    #pragma unroll
    for (int j = 0; j < 8; ++j) o[j] = f2bf(tile[8*i + j][c]);
    *(s16x8*)(d + 8*i) = o;
  }
}

// ---------------------------------------------------------------------------
// Big GEMM: P[s] = adj[:, kslice] @ B[kslice, :]   (bf16 MFMA, fp32 accum)
// BM=96, BN=256, BK=32, 4 waves, wave tile 96x64 (M_rep=6, N_rep=4).
// 2-phase pipeline: double-buffered LDS, prefetch next step's globals into
// regs before compute, ds_write + one barrier per step.
// L0: A source is fp32 adj; converted tiles are also stored to adjb (bf16).
// else: A source is adjb (bf16), half the HBM bytes.
// ---------------------------------------------------------------------------
template<bool L0>
__global__ __launch_bounds__(256) void k_gemm(const float* __restrict__ adjf,
                                              short* __restrict__ adjb,
                                              const short* __restrict__ BT,
                                              float* __restrict__ Pbase, int S){
  __shared__ short Alds[2][96 * 32];    // [buf][row][slot^swz(row)][8]
  __shared__ short Blds[2][256 * 32];   // [buf][col][slot^swz(col)][8]

  const int t  = threadIdx.x;
  const int bm = blockIdx.x;
  const int s  = blockIdx.y;
  const int per = STEPS_TOTAL / S, rem = STEPS_TOTAL % S;
  const int st0 = s * per + (s < rem ? s : rem);
  const int nst = per + (s < rem ? 1 : 0);

  const int l  = t & 63, w = t >> 6;
  const int lr = l & 15, lg = l >> 4;
  const int fswz = (lr >> 1) & 3;

  f32x4 acc[6][4];
  #pragma unroll
  for (int m = 0; m < 6; ++m)
    #pragma unroll
    for (int j = 0; j < 4; ++j) acc[m][j] = (f32x4)(0.0f);

  // staging roles
  const int ar = t >> 1, ah = t & 1;                   // A: t<192, row ar, half ah
  const size_t arow_off = (size_t)(bm * 96 + ar) * K_DIM + ah * 16;
  const int aswz = (ar >> 1) & 3;
  const short* bptr = BT + (size_t)t * K_DIM;          // B: col t
  const int bswz = (t >> 1) & 3;

  s16x8 av0, av1, bv[4];

  // ---- prologue: load + stage step 0 ----
  {
    const int kk = st0 * 32;
    #pragma unroll
    for (int i = 0; i < 4; ++i) bv[i] = *(const s16x8*)(bptr + kk + 8*i);
    if (t < 192){
      if (L0){
        const float* ap = adjf + arow_off + kk;
        f32x4 f0 = *(const f32x4*)(ap + 0);
        f32x4 f1 = *(const f32x4*)(ap + 4);
        #pragma unroll
        for (int j = 0; j < 4; ++j){ av0[j] = f2bf(f0[j]); av0[4+j] = f2bf(f1[j]); }
        f32x4 f2 = *(const f32x4*)(ap + 8);
        f32x4 f3 = *(const f32x4*)(ap + 12);
        #pragma unroll
        for (int j = 0; j < 4; ++j){ av1[j] = f2bf(f2[j]); av1[4+j] = f2bf(f3[j]); }
        *(s16x8*)(adjb + arow_off + kk)     = av0;
        *(s16x8*)(adjb + arow_off + kk + 8) = av1;
      } else {
        const short* ap = adjb + arow_off + kk;
        av0 = *(const s16x8*)(ap);
        av1 = *(const s16x8*)(ap + 8);
      }
    }
    #pragma unroll
    for (int i = 0; i < 4; ++i)
      *(s16x8*)(&Blds[0][t * 32 + ((i ^ bswz) * 8)]) = bv[i];
    if (t < 192){
      *(s16x8*)(&Alds[0][ar * 32 + (((2*ah    ) ^ aswz) * 8)]) = av0;
      *(s16x8*)(&Alds[0][ar * 32 + (((2*ah + 1) ^ aswz) * 8)]) = av1;
    }
  }
  __syncthreads();

  int cur = 0;
  for (int stp = 0; stp < nst; ++stp){
    const bool more = (stp + 1 < nst);

    // ---- issue next step's global loads (latency hidden under MFMA) ----
    if (more){
      const int kk = (st0 + stp + 1) * 32;
      #pragma unroll
      for (int i = 0; i < 4; ++i) bv[i] = *(const s16x8*)(bptr + kk + 8*i);
      if (t < 192){
        if (L0){
          const float* ap = adjf + arow_off + kk;
          f32x4 f0 = *(const f32x4*)(ap + 0);
          f32x4 f1 = *(const f32x4*)(ap + 4);
          #pragma unroll
          for (int j = 0; j < 4; ++j){ av0[j] = f2bf(f0[j]); av0[4+j] = f2bf(f1[j]); }
          f32x4 f2 = *(const f32x4*)(ap + 8);
          f32x4 f3 = *(const f32x4*)(ap + 12);
          #pragma unroll
          for (int j = 0; j < 4; ++j){ av1[j] = f2bf(f2[j]); av1[4+j] = f2bf(f3[j]); }
        } else {
          const short* ap = adjb + arow_off + kk;
          av0 = *(const s16x8*)(ap);
          av1 = *(const s16x8*)(ap + 8);
        }
      }
    }

    // ---- compute on buf[cur] ----
    s16x8 af[6], bf[4];
    #pragma unroll
    for (int m = 0; m < 6; ++m)
      af[m] = *(const s16x8*)(&Alds[cur][(16*m + lr) * 32 + ((lg ^ fswz) * 8)]);
    #pragma unroll
    for (int j = 0; j < 4; ++j)
      bf[j] = *(const s16x8*)(&Blds[cur][(w*64 + j*16 + lr) * 32 + ((lg ^ fswz) * 8)]);

    #pragma unroll
    for (int m = 0; m < 6; ++m)
      #pragma unroll
      for (int j = 0; j < 4; ++j)
        acc[m][j] = mfma16(af[m], bf[j], acc[m][j]);

    // ---- stage next step into buf[cur^1], one barrier per step ----
    if (more){
      const int kk = (st0 + stp + 1) * 32;
      if (L0 && t < 192){
        *(s16x8*)(adjb + arow_off + kk)     = av0;
        *(s16x8*)(adjb + arow_off + kk + 8) = av1;
      }
      #pragma unroll
      for (int i = 0; i < 4; ++i)
        *(s16x8*)(&Blds[cur^1][t * 32 + ((i ^ bswz) * 8)]) = bv[i];
      if (t < 192){
        *(s16x8*)(&Alds[cur^1][ar * 32 + (((2*ah    ) ^ aswz) * 8)]) = av0;
        *(s16x8*)(&Alds[cur^1][ar * 32 + (((2*ah + 1) ^ aswz) * 8)]) = av1;
      }
      __syncthreads();
      cur ^= 1;
    }
  }

  // epilogue: C/D layout col=lane&15, row=(lane>>4)*4+reg
  float* P = Pbase + (size_t)s * M_ROWS * FEAT;
  #pragma unroll
  for (int m = 0; m < 6; ++m){
    const int row = bm * 96 + 16*m + lg * 4;
    #pragma unroll
    for (int j = 0; j < 4; ++j){
      const int col = w*64 + j*16 + lr;
      float* p = P + (size_t)row * FEAT + col;
      #pragma unroll
      for (int r = 0; r < 4; ++r) p[(size_t)r * FEAT] = acc[m][j][r];
    }
  }
}

// ---------------------------------------------------------------------------
// HbT = transpose(l2norm_rows(relu((sum_s P[s]) @ W + b))) as bf16 [256][12000]
// block = 32 rows, thread = 4x8 register tile, fp32 compute
// ---------------------------------------------------------------------------
__global__ __launch_bounds__(256) void k_fused2(const float* __restrict__ Pbase, int S,
                                                const float* __restrict__ W,
                                                const float* __restrict__ b,
                                                short* __restrict__ HbT){
  __shared__ float ylds[32][257];
  __shared__ float red[32][33];
  __shared__ float scale[32];
  const int t  = threadIdx.x;
  const int r0 = blockIdx.x * 32;
  {
    const int r = t >> 3, cs = (t & 7) * 32;
    const size_t off = (size_t)(r0 + r) * FEAT + cs;
    f32x4 a4[8];
    #pragma unroll
    for (int i = 0; i < 8; ++i) a4[i] = *(const f32x4*)(Pbase + off + 4*i);
    for (int s = 1; s < S; ++s){
      const float* ps = Pbase + (size_t)s * M_ROWS * FEAT + off;
      #pragma unroll
      for (int i = 0; i < 8; ++i) a4[i] += *(const f32x4*)(ps + 4*i);
    }
    #pragma unroll
    for (int i = 0; i < 8; ++i){
      ylds[r][cs + 4*i + 0] = a4[i][0];
      ylds[r][cs + 4*i + 1] = a4[i][1];
      ylds[r][cs + 4*i + 2] = a4[i][2];
      ylds[r][cs + 4*i + 3] = a4[i][3];
    }
  }
  __syncthreads();

  const int rg = t >> 5;   // rows rg*4 .. rg*4+3
  const int cg = t & 31;   // cols cg*8 .. cg*8+7
  float acc[4][8];
  {
    float bias[8];
    #pragma unroll
    for (int j = 0; j < 8; ++j) bias[j] = b[cg*8 + j];
    #pragma unroll
    for (int i = 0; i < 4; ++i)
      #pragma unroll
      for (int j = 0; j < 8; ++j) acc[i][j] = bias[j];
  }

  #pragma unroll 4
  for (int k = 0; k < FEAT; ++k){
    float yv[4];
    #pragma unroll
    for (int i = 0; i < 4; ++i) yv[i] = ylds[rg*4 + i][k];
    f32x4 w0 = *(const f32x4*)(W + (size_t)k * FEAT + cg*8);
    f32x4 w1 = *(const f32x4*)(W + (size_t)k * FEAT + cg*8 + 4);
    #pragma unroll
    for (int i = 0; i < 4; ++i){
      #pragma unroll
      for (int j = 0; j < 4; ++j){
        acc[i][j]     += yv[i] * w0[j];
        acc[i][4 + j] += yv[i] * w1[j];
      }
    }
  }

  #pragma unroll
  for (int i = 0; i < 4; ++i){
    float ss = 0.0f;
    #pragma unroll
    for (int j = 0; j < 8; ++j){
      float v = fmaxf(acc[i][j], 0.0f);
      acc[i][j] = v;
      ss += v * v;
    }
    red[rg*4 + i][cg] = ss;
  }
  __syncthreads();
  if (t < 32){
    float ssum = 0.0f;
    #pragma unroll
    for (int j = 0; j < 32; ++j) ssum += red[t][j];
    scale[t] = 1.0f / fmaxf(sqrtf(ssum), 1e-12f);
  }
  __syncthreads();

  float sc[4];
  #pragma unroll
  for (int i = 0; i < 4; ++i) sc[i] = scale[rg*4 + i];
  #pragma unroll
  for (int j = 0; j < 8; ++j){
    s16x4 o;
    #pragma unroll
    for (int i = 0; i < 4; ++i) o[i] = f2bf(acc[i][j] * sc[i]);
    *(s16x4*)(HbT + (size_t)(cg*8 + j) * M_ROWS + r0 + rg*4) = o;
  }
}

// ---------------------------------------------------------------------------
// out = (sum_s P[s]) @ W2 + b2    (12000 x 40)
// ---------------------------------------------------------------------------
__global__ __launch_bounds__(256) void k_final2(const float* __restrict__ Pbase, int S,
                                                const float* __restrict__ W2,
                                                const float* __restrict__ b2,
                                                float* __restrict__ out){
  __shared__ float ylds[32][257];
  const int t  = threadIdx.x;
  const int r0 = blockIdx.x * 32;
  {
    const int r = t >> 3, cs = (t & 7) * 32;
    const size_t off = (size_t)(r0 + r) * FEAT + cs;
    f32x4 a4[8];
    #pragma unroll
    for (int i = 0; i < 8; ++i) a4[i] = *(const f32x4*)(Pbase + off + 4*i);
    for (int s = 1; s < S; ++s){
      const float* ps = Pbase + (size_t)s * M_ROWS * FEAT + off;
      #pragma unroll
      for (int i = 0; i < 8; ++i) a4[i] += *(const f32x4*)(ps + 4*i);
    }
    #pragma unroll
    for (int i = 0; i < 8; ++i){
      ylds[r][cs + 4*i + 0] = a4[i][0];
      ylds[r][cs + 4*i + 1] = a4[i][1];
      ylds[r][cs + 4*i + 2] = a4[i][2];
      ylds[r][cs + 4*i + 3] = a4[i][3];
    }
  }
  __syncthreads();

  #pragma unroll
  for (int e = t; e < 32 * NCLS; e += 256){
    const int r = e / NCLS, n = e % NCLS;
    float a = b2[n];
    #pragma unroll 8
    for (int k = 0; k < FEAT; ++k)
      a = fmaf(ylds[r][k], W2[(size_t)k * NCLS + n], a);
    out[(size_t)(r0 + r) * NCLS + n] = a;
  }
}

// ---------------------------------------------------------------------------
extern "C" void kernel_launch(void* const* d_in, const int* in_sizes, int n_in,
                              void* d_out, int out_size, void* d_ws, size_t ws_size,
                              hipStream_t stream){
  const float* adj = (const float*)d_in[0];
  const float* x   = (const float*)d_in[1];
  const float* W0  = (const float*)d_in[2];
  const float* b0  = (const float*)d_in[3];
  const float* W1  = (const float*)d_in[4];
  const float* b1  = (const float*)d_in[5];
  const float* W2  = (const float*)d_in[6];
  const float* b2  = (const float*)d_in[7];
  float* out = (float*)d_out;

  char* ws = (char*)d_ws;
  const size_t HBT_BYTES  = (size_t)FEAT * M_ROWS * 2;           //   6,144,000
  const size_t ADJB_BYTES = (size_t)M_ROWS * K_DIM * 2;          // 288,000,000
  const size_t SLAB       = (size_t)M_ROWS * FEAT * 4;           //  12,288,000

  short* HbT  = (short*)ws;
  short* adjb = (short*)(ws + HBT_BYTES);
  float* P    = (float*)(ws + HBT_BYTES + ADJB_BYTES);

  int smax = (ws_size > HBT_BYTES + ADJB_BYTES)
               ? (int)((ws_size - HBT_BYTES - ADJB_BYTES) / SLAB) : 1;
  int S = smax < 6 ? smax : 6;
  if (S < 1) S = 1;

  const dim3 b256(256);

  k_transpose_bf16<<<375, b256, 0, stream>>>(x, HbT);

  // layer 0: fp32 adj -> bf16 adjb cached in-flight
  k_gemm<true><<<dim3(125, S), b256, 0, stream>>>(adj, adjb, HbT, P, S);
  k_fused2<<<375, b256, 0, stream>>>(P, S, W0, b0, HbT);

  // layer 1
  k_gemm<false><<<dim3(125, S), b256, 0, stream>>>(nullptr, adjb, HbT, P, S);
  k_fused2<<<375, b256, 0, stream>>>(P, S, W1, b1, HbT);

  // layer 2
  k_gemm<false><<<dim3(125, S), b256, 0, stream>>>(nullptr, adjb, HbT, P, S);
  k_final2<<<375, b256, 0, stream>>>(P, S, W2, b2, out);
}

// Round 3
// 634.102 us; speedup vs baseline: 1.3475x; 1.3475x over previous
//
#include <hip/hip_runtime.h>
#include <hip/hip_bf16.h>

#define M_ROWS 12000
#define K_PAD  12032          // 376 * 32
#define FEAT   256
#define NCLS   40
#define NSLICE 5
#define UNITS  376            // K_PAD / 32
#define PSLAB  (K_PAD * FEAT) // floats per P slab (12032 padded rows x 256)

typedef __attribute__((ext_vector_type(4))) float f32x4;
typedef __attribute__((ext_vector_type(8))) short s16x8;
typedef __attribute__((ext_vector_type(4))) short s16x4;
typedef unsigned int u32;

__device__ __forceinline__ short f2bf(float f){
  __hip_bfloat16 h = __float2bfloat16(f);
  union { __hip_bfloat16 h; short s; } u; u.h = h; return u.s;
}

__device__ __forceinline__ f32x4 mfma16(s16x8 a, s16x8 b, f32x4 c){
  return __builtin_amdgcn_mfma_f32_16x16x32_bf16(a, b, c, 0, 0, 0);
}

__device__ __forceinline__ void gl16(const void* g, void* l){
  __builtin_amdgcn_global_load_lds(
      (const __attribute__((address_space(1))) u32*)g,
      (__attribute__((address_space(3))) u32*)l, 16, 0, 0);
}

#define VM0   do { asm volatile("s_waitcnt vmcnt(0)" ::: "memory"); \
                   __builtin_amdgcn_sched_barrier(0); } while(0)
#define BARR  do { __builtin_amdgcn_s_barrier(); \
                   __builtin_amdgcn_sched_barrier(0); } while(0)

// ---------------------------------------------------------------------------
// adj fp32 [12000][12000] -> adjb bf16 [12000][K_PAD], zero-padded tail cols
// ---------------------------------------------------------------------------
__global__ __launch_bounds__(256) void k_convert(const float* __restrict__ adj,
                                                 short* __restrict__ adjb){
  const int r = blockIdx.x;
  const float* src = adj + (size_t)r * M_ROWS;
  short* dst = adjb + (size_t)r * K_PAD;
  for (int c0 = threadIdx.x * 4; c0 < K_PAD; c0 += 1024){
    s16x4 o;
    if (c0 < M_ROWS){
      f32x4 v = *(const f32x4*)(src + c0);
      #pragma unroll
      for (int j = 0; j < 4; ++j) o[j] = f2bf(v[j]);
    } else {
      o = (s16x4)0;
    }
    *(s16x4*)(dst + c0) = o;
  }
}

// ---------------------------------------------------------------------------
// zero HbT tail columns [12000..K_PAD)
// ---------------------------------------------------------------------------
__global__ __launch_bounds__(256) void k_zerotail(short* __restrict__ HbT){
  const int t = threadIdx.x;   // one thread per HbT row (256 rows)
  short* d = HbT + (size_t)t * K_PAD + M_ROWS;
  s16x8 z = (s16x8)0;
  #pragma unroll
  for (int i = 0; i < 4; ++i) *(s16x8*)(d + 8*i) = z;
}

// ---------------------------------------------------------------------------
// fp32 x [12000][256] -> bf16 HbT [256][K_PAD] (transposed)
// ---------------------------------------------------------------------------
__global__ __launch_bounds__(256) void k_transpose_bf16(const float* __restrict__ src,
                                                        short* __restrict__ dst){
  __shared__ float tile[32][257];
  const int t  = threadIdx.x;
  const int r0 = blockIdx.x * 32;
  {
    const int r = t >> 3, cs = (t & 7) * 32;
    const float* s = src + (size_t)(r0 + r) * FEAT + cs;
    #pragma unroll
    for (int i = 0; i < 8; ++i){
      f32x4 v = *(const f32x4*)(s + 4*i);
      tile[r][cs + 4*i + 0] = v[0];
      tile[r][cs + 4*i + 1] = v[1];
      tile[r][cs + 4*i + 2] = v[2];
      tile[r][cs + 4*i + 3] = v[3];
    }
  }
  __syncthreads();
  const int c = t;
  short* d = dst + (size_t)c * K_PAD + r0;
  #pragma unroll
  for (int i = 0; i < 4; ++i){
    s16x8 o;
    #pragma unroll
    for (int j = 0; j < 8; ++j) o[j] = f2bf(tile[8*i + j][c]);
    *(s16x8*)(d + 8*i) = o;
  }
}

// ---------------------------------------------------------------------------
// Big GEMM: P[s] = adjb[:, kslice] @ HbT^T[kslice, :]
// BM=128, BN=256, BK=32, 512 threads (8 waves, 2Mx4N), wave tile 64x64.
// All staging via global_load_lds (pre-swizzled global src, linear LDS dest,
// XOR-swizzled reads). Double-buffered LDS (48 KB), 2 blocks/CU.
// Loop: STAGE(t+1) -> ds_read frags -> 16 MFMA -> vmcnt(0) -> s_barrier.
// ---------------------------------------------------------------------------
__global__ __launch_bounds__(512, 4) void k_gemm8(const short* __restrict__ Abase,
                                                  const short* __restrict__ Bbase,
                                                  float* __restrict__ Pbase){
  // per buffer: A[128][32] = 4096 shorts, B[256][32] = 8192 shorts
  __shared__ short lds[2][12288];

  const int t  = threadIdx.x;
  const int w  = t >> 6, l = t & 63;
  const int wm = w >> 2, wn = w & 3;
  const int lr = l & 15, lg = l >> 4;
  const int swl = lr & 3;

  const int bm   = blockIdx.x;           // 0..93
  const int s    = blockIdx.y;           // 0..NSLICE-1
  const int row0 = bm * 128;
  const int u0   = s * 75 + (s >= 1 ? 1 : 0);   // slice start (units of 32)
  const int nu   = 75 + (s == 0 ? 1 : 0);       // 76,75,75,75,75 -> 376

  // --- staging source pointers (pre-swizzled global addresses) ---
  // A: 1 instr/wave: local row r = t>>2, 16B slot sl = t&3
  const short* asrc;
  {
    const int r = t >> 2, sl = t & 3;
    int grow = row0 + r; if (grow > M_ROWS - 1) grow = M_ROWS - 1;
    asrc = Abase + (size_t)grow * K_PAD + ((sl ^ (r & 3)) * 8);
  }
  // B: 2 instr/wave: col c = (j*512+t)>>2, slot sl = t&3
  const short* bsrc0;
  const short* bsrc1;
  {
    const int sl = t & 3;
    const int c0 = t >> 2;           // j=0: 0..127
    const int c1 = (512 + t) >> 2;   // j=1: 128..255
    bsrc0 = Bbase + (size_t)c0 * K_PAD + ((sl ^ (c0 & 3)) * 8);
    bsrc1 = Bbase + (size_t)c1 * K_PAD + ((sl ^ (c1 & 3)) * 8);
  }

  f32x4 acc[4][4];
  #pragma unroll
  for (int m = 0; m < 4; ++m)
    #pragma unroll
    for (int n = 0; n < 4; ++n) acc[m][n] = (f32x4)(0.0f);

#define STAGE(q, kk)                                                       \
  do {                                                                     \
    gl16(asrc  + (kk), &lds[q][w * 512]);                                  \
    gl16(bsrc0 + (kk), &lds[q][4096 + w * 512]);                           \
    gl16(bsrc1 + (kk), &lds[q][4096 + 4096 + w * 512]);                    \
  } while(0)

  // prologue
  STAGE(0, u0 * 32);
  VM0;
  BARR;

  for (int ut = 0; ut < nu; ++ut){
    const int p = ut & 1;
    if (ut + 1 < nu) STAGE(p ^ 1, (u0 + ut + 1) * 32);

    const short* LA = &lds[p][0];
    const short* LB = &lds[p][4096];
    s16x8 af[4], bfr[4];
    #pragma unroll
    for (int m = 0; m < 4; ++m)
      af[m] = *(const s16x8*)&LA[(wm*64 + m*16 + lr) * 32 + ((lg ^ swl) * 8)];
    #pragma unroll
    for (int n = 0; n < 4; ++n)
      bfr[n] = *(const s16x8*)&LB[(wn*64 + n*16 + lr) * 32 + ((lg ^ swl) * 8)];

    __builtin_amdgcn_s_setprio(1);
    #pragma unroll
    for (int m = 0; m < 4; ++m)
      #pragma unroll
      for (int n = 0; n < 4; ++n)
        acc[m][n] = mfma16(af[m], bfr[n], acc[m][n]);
    __builtin_amdgcn_s_setprio(0);

    VM0;    // next tile's DMA has landed (issued one full phase ago)
    BARR;
  }
#undef STAGE

  // epilogue: C/D layout col=lane&15, row=(lane>>4)*4+reg
  float* P = Pbase + (size_t)s * PSLAB;
  #pragma unroll
  for (int m = 0; m < 4; ++m){
    const int row = row0 + wm*64 + m*16 + lg*4;
    #pragma unroll
    for (int n = 0; n < 4; ++n){
      const int col = wn*64 + n*16 + lr;
      float* pp = P + (size_t)row * FEAT + col;
      #pragma unroll
      for (int r = 0; r < 4; ++r) pp[(size_t)r * FEAT] = acc[m][n][r];
    }
  }
}

// ---------------------------------------------------------------------------
// HbT = transpose(l2norm_rows(relu((sum_s P[s]) @ W + b))) as bf16 [256][K_PAD]
// ---------------------------------------------------------------------------
__global__ __launch_bounds__(256) void k_fused2(const float* __restrict__ Pbase,
                                                const float* __restrict__ W,
                                                const float* __restrict__ b,
                                                short* __restrict__ HbT){
  __shared__ float ylds[32][257];
  __shared__ float red[32][33];
  __shared__ float scale[32];
  const int t  = threadIdx.x;
  const int r0 = blockIdx.x * 32;
  {
    const int r = t >> 3, cs = (t & 7) * 32;
    const size_t off = (size_t)(r0 + r) * FEAT + cs;
    f32x4 a4[8];
    #pragma unroll
    for (int i = 0; i < 8; ++i) a4[i] = *(const f32x4*)(Pbase + off + 4*i);
    #pragma unroll
    for (int s = 1; s < NSLICE; ++s){
      const float* ps = Pbase + (size_t)s * PSLAB + off;
      #pragma unroll
      for (int i = 0; i < 8; ++i) a4[i] += *(const f32x4*)(ps + 4*i);
    }
    #pragma unroll
    for (int i = 0; i < 8; ++i){
      ylds[r][cs + 4*i + 0] = a4[i][0];
      ylds[r][cs + 4*i + 1] = a4[i][1];
      ylds[r][cs + 4*i + 2] = a4[i][2];
      ylds[r][cs + 4*i + 3] = a4[i][3];
    }
  }
  __syncthreads();

  const int rg = t >> 5;   // rows rg*4 .. rg*4+3
  const int cg = t & 31;   // cols cg*8 .. cg*8+7
  float acc[4][8];
  {
    float bias[8];
    #pragma unroll
    for (int j = 0; j < 8; ++j) bias[j] = b[cg*8 + j];
    #pragma unroll
    for (int i = 0; i < 4; ++i)
      #pragma unroll
      for (int j = 0; j < 8; ++j) acc[i][j] = bias[j];
  }

  #pragma unroll 4
  for (int k = 0; k < FEAT; ++k){
    float yv[4];
    #pragma unroll
    for (int i = 0; i < 4; ++i) yv[i] = ylds[rg*4 + i][k];
    f32x4 w0 = *(const f32x4*)(W + (size_t)k * FEAT + cg*8);
    f32x4 w1 = *(const f32x4*)(W + (size_t)k * FEAT + cg*8 + 4);
    #pragma unroll
    for (int i = 0; i < 4; ++i){
      #pragma unroll
      for (int j = 0; j < 4; ++j){
        acc[i][j]     += yv[i] * w0[j];
        acc[i][4 + j] += yv[i] * w1[j];
      }
    }
  }

  #pragma unroll
  for (int i = 0; i < 4; ++i){
    float ss = 0.0f;
    #pragma unroll
    for (int j = 0; j < 8; ++j){
      float v = fmaxf(acc[i][j], 0.0f);
      acc[i][j] = v;
      ss += v * v;
    }
    red[rg*4 + i][cg] = ss;
  }
  __syncthreads();
  if (t < 32){
    float ssum = 0.0f;
    #pragma unroll
    for (int j = 0; j < 32; ++j) ssum += red[t][j];
    scale[t] = 1.0f / fmaxf(sqrtf(ssum), 1e-12f);
  }
  __syncthreads();

  float sc[4];
  #pragma unroll
  for (int i = 0; i < 4; ++i) sc[i] = scale[rg*4 + i];
  #pragma unroll
  for (int j = 0; j < 8; ++j){
    s16x4 o;
    #pragma unroll
    for (int i = 0; i < 4; ++i) o[i] = f2bf(acc[i][j] * sc[i]);
    *(s16x4*)(HbT + (size_t)(cg*8 + j) * K_PAD + r0 + rg*4) = o;
  }
}

// ---------------------------------------------------------------------------
// out = (sum_s P[s]) @ W2 + b2    (12000 x 40)
// ---------------------------------------------------------------------------
__global__ __launch_bounds__(256) void k_final2(const float* __restrict__ Pbase,
                                                const float* __restrict__ W2,
                                                const float* __restrict__ b2,
                                                float* __restrict__ out){
  __shared__ float ylds[32][257];
  const int t  = threadIdx.x;
  const int r0 = blockIdx.x * 32;
  {
    const int r = t >> 3, cs = (t & 7) * 32;
    const size_t off = (size_t)(r0 + r) * FEAT + cs;
    f32x4 a4[8];
    #pragma unroll
    for (int i = 0; i < 8; ++i) a4[i] = *(const f32x4*)(Pbase + off + 4*i);
    #pragma unroll
    for (int s = 1; s < NSLICE; ++s){
      const float* ps = Pbase + (size_t)s * PSLAB + off;
      #pragma unroll
      for (int i = 0; i < 8; ++i) a4[i] += *(const f32x4*)(ps + 4*i);
    }
    #pragma unroll
    for (int i = 0; i < 8; ++i){
      ylds[r][cs + 4*i + 0] = a4[i][0];
      ylds[r][cs + 4*i + 1] = a4[i][1];
      ylds[r][cs + 4*i + 2] = a4[i][2];
      ylds[r][cs + 4*i + 3] = a4[i][3];
    }
  }
  __syncthreads();

  #pragma unroll
  for (int e = t; e < 32 * NCLS; e += 256){
    const int r = e / NCLS, n = e % NCLS;
    float a = b2[n];
    #pragma unroll 8
    for (int k = 0; k < FEAT; ++k)
      a = fmaf(ylds[r][k], W2[(size_t)k * NCLS + n], a);
    out[(size_t)(r0 + r) * NCLS + n] = a;
  }
}

// ---------------------------------------------------------------------------
extern "C" void kernel_launch(void* const* d_in, const int* in_sizes, int n_in,
                              void* d_out, int out_size, void* d_ws, size_t ws_size,
                              hipStream_t stream){
  const float* adj = (const float*)d_in[0];
  const float* x   = (const float*)d_in[1];
  const float* W0  = (const float*)d_in[2];
  const float* b0  = (const float*)d_in[3];
  const float* W1  = (const float*)d_in[4];
  const float* b1  = (const float*)d_in[5];
  const float* W2  = (const float*)d_in[6];
  const float* b2  = (const float*)d_in[7];
  float* out = (float*)d_out;

  char* ws = (char*)d_ws;
  const size_t HBT_BYTES  = (size_t)FEAT * K_PAD * 2;      //   6,160,384
  const size_t ADJB_BYTES = (size_t)M_ROWS * K_PAD * 2;    // 288,768,000

  short* HbT  = (short*)ws;
  short* adjb = (short*)(ws + HBT_BYTES);
  float* P    = (float*)(ws + HBT_BYTES + ADJB_BYTES);

  const dim3 b256(256), b512(512);
  const dim3 ggrid(94, NSLICE);

  k_convert<<<M_ROWS, b256, 0, stream>>>(adj, adjb);
  k_zerotail<<<1, b256, 0, stream>>>(HbT);
  k_transpose_bf16<<<375, b256, 0, stream>>>(x, HbT);

  // layer 0
  k_gemm8<<<ggrid, b512, 0, stream>>>(adjb, HbT, P);
  k_fused2<<<375, b256, 0, stream>>>(P, W0, b0, HbT);
  // layer 1
  k_gemm8<<<ggrid, b512, 0, stream>>>(adjb, HbT, P);
  k_fused2<<<375, b256, 0, stream>>>(P, W1, b1, HbT);
  // layer 2
  k_gemm8<<<ggrid, b512, 0, stream>>>(adjb, HbT, P);
  k_final2<<<375, b256, 0, stream>>>(P, W2, b2, out);
}

// Round 4
// 580.662 us; speedup vs baseline: 1.4715x; 1.0920x over previous
//
#include <hip/hip_runtime.h>
#include <hip/hip_bf16.h>

#define M_ROWS 12000
#define K_PAD  12032          // 376 * 32
#define FEAT   256
#define NCLS   40
#define NSLICE 5
#define UNITS  376            // K_PAD / 32
#define PSLAB  (K_PAD * FEAT) // floats per P slab

typedef __attribute__((ext_vector_type(4))) float f32x4;
typedef __attribute__((ext_vector_type(8))) short s16x8;
typedef __attribute__((ext_vector_type(4))) short s16x4;
typedef unsigned int u32;

__device__ __forceinline__ short f2bf(float f){
  __hip_bfloat16 h = __float2bfloat16(f);
  union { __hip_bfloat16 h; short s; } u; u.h = h; return u.s;
}

__device__ __forceinline__ f32x4 mfma16(s16x8 a, s16x8 b, f32x4 c){
  return __builtin_amdgcn_mfma_f32_16x16x32_bf16(a, b, c, 0, 0, 0);
}

__device__ __forceinline__ void gl16(const void* g, void* l){
  __builtin_amdgcn_global_load_lds(
      (const __attribute__((address_space(1))) u32*)g,
      (__attribute__((address_space(3))) u32*)l, 16, 0, 0);
}

#define VM8   do { asm volatile("s_waitcnt vmcnt(8)" ::: "memory"); \
                   __builtin_amdgcn_sched_barrier(0); } while(0)
#define VM4   do { asm volatile("s_waitcnt vmcnt(4)" ::: "memory"); \
                   __builtin_amdgcn_sched_barrier(0); } while(0)
#define VM0   do { asm volatile("s_waitcnt vmcnt(0)" ::: "memory"); \
                   __builtin_amdgcn_sched_barrier(0); } while(0)
#define BARR  do { __builtin_amdgcn_s_barrier(); \
                   __builtin_amdgcn_sched_barrier(0); } while(0)

// ---------------------------------------------------------------------------
// adj fp32 [12000][12000] -> adjb bf16 [12000][K_PAD], zero-padded tail cols
// ---------------------------------------------------------------------------
__global__ __launch_bounds__(256) void k_convert(const float* __restrict__ adj,
                                                 short* __restrict__ adjb){
  const int r = blockIdx.x;
  const float* src = adj + (size_t)r * M_ROWS;
  short* dst = adjb + (size_t)r * K_PAD;
  for (int c0 = threadIdx.x * 4; c0 < K_PAD; c0 += 1024){
    s16x4 o;
    if (c0 < M_ROWS){
      f32x4 v = *(const f32x4*)(src + c0);
      #pragma unroll
      for (int j = 0; j < 4; ++j) o[j] = f2bf(v[j]);
    } else {
      o = (s16x4)0;
    }
    *(s16x4*)(dst + c0) = o;
  }
}

// ---------------------------------------------------------------------------
// zero HbT tail columns [12000..K_PAD)
// ---------------------------------------------------------------------------
__global__ __launch_bounds__(256) void k_zerotail(short* __restrict__ HbT){
  const int t = threadIdx.x;   // one thread per HbT row (256 rows)
  short* d = HbT + (size_t)t * K_PAD + M_ROWS;
  s16x8 z = (s16x8)0;
  #pragma unroll
  for (int i = 0; i < 4; ++i) *(s16x8*)(d + 8*i) = z;
}

// ---------------------------------------------------------------------------
// fp32 x [12000][256] -> bf16 HbT [256][K_PAD] (transposed)
// ---------------------------------------------------------------------------
__global__ __launch_bounds__(256) void k_transpose_bf16(const float* __restrict__ src,
                                                        short* __restrict__ dst){
  __shared__ float tile[32][257];
  const int t  = threadIdx.x;
  const int r0 = blockIdx.x * 32;
  {
    const int r = t >> 3, cs = (t & 7) * 32;
    const float* s = src + (size_t)(r0 + r) * FEAT + cs;
    #pragma unroll
    for (int i = 0; i < 8; ++i){
      f32x4 v = *(const f32x4*)(s + 4*i);
      tile[r][cs + 4*i + 0] = v[0];
      tile[r][cs + 4*i + 1] = v[1];
      tile[r][cs + 4*i + 2] = v[2];
      tile[r][cs + 4*i + 3] = v[3];
    }
  }
  __syncthreads();
  const int c = t;
  short* d = dst + (size_t)c * K_PAD + r0;
  #pragma unroll
  for (int i = 0; i < 4; ++i){
    s16x8 o;
    #pragma unroll
    for (int j = 0; j < 8; ++j) o[j] = f2bf(tile[8*i + j][c]);
    *(s16x8*)(d + 8*i) = o;
  }
}

// ---------------------------------------------------------------------------
// Big GEMM, deep-pipelined: P[s] = adjb[:, kslice] @ HbT^T[kslice, :]
// BM=256, BN=256, BK=32. 512 threads (8 waves, 2Mx4N), wave tile 128x64.
// 4 LDS K-tile buffers (32 KB each); iteration t computes tile t (2 phases,
// 16 MFMA each, B-frags reused) while staging tile t+3 via global_load_lds.
// Counted vmcnt(8) once per iteration (tail peels 4 -> 0). Raw s_barrier.
// LDS slot swizzle: slot ^= (row&3)^((row>>2)&3)  (2-way, free) applied on
// pre-swizzled global source + swizzled ds_read (both-sides rule).
// ---------------------------------------------------------------------------
__global__ __launch_bounds__(512, 2) void k_gemm_pp(const short* __restrict__ Abase,
                                                    const short* __restrict__ Bbase,
                                                    float* __restrict__ Pbase){
  __shared__ __align__(16) short lds[4][16384];  // buf: A[256][32] @0, B[256][32] @8192

  const int t = threadIdx.x;
  const int w = t >> 6, l = t & 63;
  const int wm = w >> 2, wn = w & 3;
  const int lr = l & 15, lg = l >> 4;

  // bijective XCD-chunked swizzle of flat block id (235 = 8*29 + 3)
  int id = blockIdx.x;
  {
    const int xcd = id & 7, idx = id >> 3;
    id = (xcd < 3 ? xcd * 30 : 90 + (xcd - 3) * 29) + idx;
  }
  const int bm = id % 47, s = id / 47;
  const int row0 = bm * 256;
  const int u0   = s * 75 + (s >= 1 ? 1 : 0);   // 76,75,75,75,75 units of 32
  const int nst  = 75 + (s == 0 ? 1 : 0);

  // staging source offsets (pre-swizzled); instr j covers lds linear (j*512+t)*16B
  size_t aoff[2], boff[2];
  #pragma unroll
  for (int j = 0; j < 2; ++j){
    const int i  = j * 512 + t;
    const int r  = i >> 2, sl = i & 3;
    const int sw = (r & 3) ^ ((r >> 2) & 3);
    int grow = row0 + r; if (grow > M_ROWS - 1) grow = M_ROWS - 1;
    aoff[j] = (size_t)grow * K_PAD + (size_t)((sl ^ sw) * 8);
    boff[j] = (size_t)r    * K_PAD + (size_t)((sl ^ sw) * 8);
  }

#define STAGE_A(buf, kt) do{                                                   \
    gl16(Abase + aoff[0] + (size_t)(kt)*32, (char*)&lds[buf][0] + w*1024);     \
    gl16(Abase + aoff[1] + (size_t)(kt)*32, (char*)&lds[buf][0] + 8192 + w*1024); }while(0)
#define STAGE_B(buf, kt) do{                                                   \
    gl16(Bbase + boff[0] + (size_t)(kt)*32, (char*)&lds[buf][8192] + w*1024);  \
    gl16(Bbase + boff[1] + (size_t)(kt)*32, (char*)&lds[buf][8192] + 8192 + w*1024); }while(0)

  // ds_read addresses (shorts): row stride 32, 16B slot swizzled
#define A_FRAG(buf, mf) \
    (*(const s16x8*)&lds[buf][ (wm*128 + (mf)*16 + lr) * 32 + \
      ((lg ^ ((wm*128 + (mf)*16 + lr) & 3) ^ (((wm*128 + (mf)*16 + lr) >> 2) & 3)) * 8) ])
#define B_FRAG(buf, nf) \
    (*(const s16x8*)&lds[buf][ 8192 + (wn*64 + (nf)*16 + lr) * 32 + \
      ((lg ^ ((wn*64 + (nf)*16 + lr) & 3) ^ (((wn*64 + (nf)*16 + lr) >> 2) & 3)) * 8) ])

  f32x4 acc[8][4];
  #pragma unroll
  for (int m = 0; m < 8; ++m)
    #pragma unroll
    for (int n = 0; n < 4; ++n) acc[m][n] = (f32x4)(0.0f);

  // prologue: stage tiles 0,1,2
  STAGE_A(0, u0 + 0); STAGE_B(0, u0 + 0);
  STAGE_A(1, u0 + 1); STAGE_B(1, u0 + 1);
  STAGE_A(2, u0 + 2); STAGE_B(2, u0 + 2);
  VM8;    // tile 0 landed (8 = tiles 1,2 in flight)
  BARR;

  for (int tt = 0; tt < nst; ++tt){
    const int buf  = tt & 3;
    const int nbuf = (tt + 3) & 3;
    const bool stg = (tt + 3) < nst;
    const int ktn  = u0 + tt + 3;

    // ---- phase 0: frags + stage-A(t+3); MFMA mf 0..3 ----
    s16x8 bfr[4], af[4];
    #pragma unroll
    for (int n = 0; n < 4; ++n) bfr[n] = B_FRAG(buf, n);
    #pragma unroll
    for (int m = 0; m < 4; ++m) af[m] = A_FRAG(buf, m);
    if (stg) STAGE_A(nbuf, ktn);
    BARR;
    __builtin_amdgcn_s_setprio(1);
    #pragma unroll
    for (int m = 0; m < 4; ++m)
      #pragma unroll
      for (int n = 0; n < 4; ++n)
        acc[m][n] = mfma16(af[m], bfr[n], acc[m][n]);
    __builtin_amdgcn_s_setprio(0);
    BARR;

    // ---- phase 1: A frags mf 4..7 (B reused) + stage-B(t+3) ----
    #pragma unroll
    for (int m = 0; m < 4; ++m) af[m] = A_FRAG(buf, m + 4);
    if (stg) STAGE_B(nbuf, ktn);
    BARR;
    __builtin_amdgcn_s_setprio(1);
    #pragma unroll
    for (int m = 0; m < 4; ++m)
      #pragma unroll
      for (int n = 0; n < 4; ++n)
        acc[m + 4][n] = mfma16(af[m], bfr[n], acc[m + 4][n]);
    __builtin_amdgcn_s_setprio(0);
    if (tt + 3 < nst)      { VM8; }   // tile tt+1 landed
    else if (tt + 2 < nst) { VM4; }
    else if (tt + 1 < nst) { VM0; }
    BARR;
  }
#undef STAGE_A
#undef STAGE_B
#undef A_FRAG
#undef B_FRAG

  // epilogue: C/D layout col=lane&15, row=(lane>>4)*4+reg
  float* P = Pbase + (size_t)s * PSLAB;
  #pragma unroll
  for (int m = 0; m < 8; ++m){
    const int row = row0 + wm*128 + m*16 + lg*4;
    #pragma unroll
    for (int n = 0; n < 4; ++n){
      const int col = wn*64 + n*16 + lr;
      float* pp = P + (size_t)row * FEAT + col;
      #pragma unroll
      for (int r = 0; r < 4; ++r)
        if (row + r < M_ROWS) pp[(size_t)r * FEAT] = acc[m][n][r];
    }
  }
}

// ---------------------------------------------------------------------------
// HbT = transpose(l2norm_rows(relu((sum_s P[s]) @ W + b))) as bf16 [256][K_PAD]
// ---------------------------------------------------------------------------
__global__ __launch_bounds__(256) void k_fused2(const float* __restrict__ Pbase,
                                                const float* __restrict__ W,
                                                const float* __restrict__ b,
                                                short* __restrict__ HbT){
  __shared__ float ylds[32][257];
  __shared__ float red[32][33];
  __shared__ float scale[32];
  const int t  = threadIdx.x;
  const int r0 = blockIdx.x * 32;
  {
    const int r = t >> 3, cs = (t & 7) * 32;
    const size_t off = (size_t)(r0 + r) * FEAT + cs;
    f32x4 a4[8];
    #pragma unroll
    for (int i = 0; i < 8; ++i) a4[i] = *(const f32x4*)(Pbase + off + 4*i);
    #pragma unroll
    for (int s = 1; s < NSLICE; ++s){
      const float* ps = Pbase + (size_t)s * PSLAB + off;
      #pragma unroll
      for (int i = 0; i < 8; ++i) a4[i] += *(const f32x4*)(ps + 4*i);
    }
    #pragma unroll
    for (int i = 0; i < 8; ++i){
      ylds[r][cs + 4*i + 0] = a4[i][0];
      ylds[r][cs + 4*i + 1] = a4[i][1];
      ylds[r][cs + 4*i + 2] = a4[i][2];
      ylds[r][cs + 4*i + 3] = a4[i][3];
    }
  }
  __syncthreads();

  const int rg = t >> 5;   // rows rg*4 .. rg*4+3
  const int cg = t & 31;   // cols cg*8 .. cg*8+7
  float acc[4][8];
  {
    float bias[8];
    #pragma unroll
    for (int j = 0; j < 8; ++j) bias[j] = b[cg*8 + j];
    #pragma unroll
    for (int i = 0; i < 4; ++i)
      #pragma unroll
      for (int j = 0; j < 8; ++j) acc[i][j] = bias[j];
  }

  #pragma unroll 4
  for (int k = 0; k < FEAT; ++k){
    float yv[4];
    #pragma unroll
    for (int i = 0; i < 4; ++i) yv[i] = ylds[rg*4 + i][k];
    f32x4 w0 = *(const f32x4*)(W + (size_t)k * FEAT + cg*8);
    f32x4 w1 = *(const f32x4*)(W + (size_t)k * FEAT + cg*8 + 4);
    #pragma unroll
    for (int i = 0; i < 4; ++i){
      #pragma unroll
      for (int j = 0; j < 4; ++j){
        acc[i][j]     += yv[i] * w0[j];
        acc[i][4 + j] += yv[i] * w1[j];
      }
    }
  }

  #pragma unroll
  for (int i = 0; i < 4; ++i){
    float ss = 0.0f;
    #pragma unroll
    for (int j = 0; j < 8; ++j){
      float v = fmaxf(acc[i][j], 0.0f);
      acc[i][j] = v;
      ss += v * v;
    }
    red[rg*4 + i][cg] = ss;
  }
  __syncthreads();
  if (t < 32){
    float ssum = 0.0f;
    #pragma unroll
    for (int j = 0; j < 32; ++j) ssum += red[t][j];
    scale[t] = 1.0f / fmaxf(sqrtf(ssum), 1e-12f);
  }
  __syncthreads();

  float sc[4];
  #pragma unroll
  for (int i = 0; i < 4; ++i) sc[i] = scale[rg*4 + i];
  #pragma unroll
  for (int j = 0; j < 8; ++j){
    s16x4 o;
    #pragma unroll
    for (int i = 0; i < 4; ++i) o[i] = f2bf(acc[i][j] * sc[i]);
    *(s16x4*)(HbT + (size_t)(cg*8 + j) * K_PAD + r0 + rg*4) = o;
  }
}

// ---------------------------------------------------------------------------
// out = (sum_s P[s]) @ W2 + b2    (12000 x 40)
// ---------------------------------------------------------------------------
__global__ __launch_bounds__(256) void k_final2(const float* __restrict__ Pbase,
                                                const float* __restrict__ W2,
                                                const float* __restrict__ b2,
                                                float* __restrict__ out){
  __shared__ float ylds[32][257];
  const int t  = threadIdx.x;
  const int r0 = blockIdx.x * 32;
  {
    const int r = t >> 3, cs = (t & 7) * 32;
    const size_t off = (size_t)(r0 + r) * FEAT + cs;
    f32x4 a4[8];
    #pragma unroll
    for (int i = 0; i < 8; ++i) a4[i] = *(const f32x4*)(Pbase + off + 4*i);
    #pragma unroll
    for (int s = 1; s < NSLICE; ++s){
      const float* ps = Pbase + (size_t)s * PSLAB + off;
      #pragma unroll
      for (int i = 0; i < 8; ++i) a4[i] += *(const f32x4*)(ps + 4*i);
    }
    #pragma unroll
    for (int i = 0; i < 8; ++i){
      ylds[r][cs + 4*i + 0] = a4[i][0];
      ylds[r][cs + 4*i + 1] = a4[i][1];
      ylds[r][cs + 4*i + 2] = a4[i][2];
      ylds[r][cs + 4*i + 3] = a4[i][3];
    }
  }
  __syncthreads();

  #pragma unroll
  for (int e = t; e < 32 * NCLS; e += 256){
    const int r = e / NCLS, n = e % NCLS;
    float a = b2[n];
    #pragma unroll 8
    for (int k = 0; k < FEAT; ++k)
      a = fmaf(ylds[r][k], W2[(size_t)k * NCLS + n], a);
    out[(size_t)(r0 + r) * NCLS + n] = a;
  }
}

// ---------------------------------------------------------------------------
extern "C" void kernel_launch(void* const* d_in, const int* in_sizes, int n_in,
                              void* d_out, int out_size, void* d_ws, size_t ws_size,
                              hipStream_t stream){
  const float* adj = (const float*)d_in[0];
  const float* x   = (const float*)d_in[1];
  const float* W0  = (const float*)d_in[2];
  const float* b0  = (const float*)d_in[3];
  const float* W1  = (const float*)d_in[4];
  const float* b1  = (const float*)d_in[5];
  const float* W2  = (const float*)d_in[6];
  const float* b2  = (const float*)d_in[7];
  float* out = (float*)d_out;

  char* ws = (char*)d_ws;
  const size_t HBT_BYTES  = (size_t)FEAT * K_PAD * 2;      //   6,160,384
  const size_t ADJB_BYTES = (size_t)M_ROWS * K_PAD * 2;    // 288,768,000

  short* HbT  = (short*)ws;
  short* adjb = (short*)(ws + HBT_BYTES);
  float* P    = (float*)(ws + HBT_BYTES + ADJB_BYTES);

  const dim3 b256(256), b512(512);

  k_convert<<<M_ROWS, b256, 0, stream>>>(adj, adjb);
  k_zerotail<<<1, b256, 0, stream>>>(HbT);
  k_transpose_bf16<<<375, b256, 0, stream>>>(x, HbT);

  // layer 0
  k_gemm_pp<<<47 * NSLICE, b512, 0, stream>>>(adjb, HbT, P);
  k_fused2<<<375, b256, 0, stream>>>(P, W0, b0, HbT);
  // layer 1
  k_gemm_pp<<<47 * NSLICE, b512, 0, stream>>>(adjb, HbT, P);
  k_fused2<<<375, b256, 0, stream>>>(P, W1, b1, HbT);
  // layer 2
  k_gemm_pp<<<47 * NSLICE, b512, 0, stream>>>(adjb, HbT, P);
  k_final2<<<375, b256, 0, stream>>>(P, W2, b2, out);
}

// Round 5
// 574.963 us; speedup vs baseline: 1.4861x; 1.0099x over previous
//
#include <hip/hip_runtime.h>
#include <hip/hip_bf16.h>

#define M_ROWS 12000
#define K_PAD  12032          // 188 * 64
#define FEAT   256
#define NCLS   40
#define NSLICE 5
#define PSLAB  (K_PAD * FEAT) // floats per P slab

typedef __attribute__((ext_vector_type(4))) float f32x4;
typedef __attribute__((ext_vector_type(8))) short s16x8;
typedef __attribute__((ext_vector_type(4))) short s16x4;
typedef unsigned int u32;

__device__ __forceinline__ short f2bf(float f){
  __hip_bfloat16 h = __float2bfloat16(f);
  union { __hip_bfloat16 h; short s; } u; u.h = h; return u.s;
}

__device__ __forceinline__ f32x4 mfma16(s16x8 a, s16x8 b, f32x4 c){
  return __builtin_amdgcn_mfma_f32_16x16x32_bf16(a, b, c, 0, 0, 0);
}

__device__ __forceinline__ void gl16(const void* g, void* l){
  __builtin_amdgcn_global_load_lds(
      (const __attribute__((address_space(1))) u32*)g,
      (__attribute__((address_space(3))) u32*)l, 16, 0, 0);
}

#define VM4   do { asm volatile("s_waitcnt vmcnt(4)" ::: "memory"); \
                   __builtin_amdgcn_sched_barrier(0); } while(0)
#define VM0   do { asm volatile("s_waitcnt vmcnt(0)" ::: "memory"); \
                   __builtin_amdgcn_sched_barrier(0); } while(0)
#define BARR  do { __builtin_amdgcn_s_barrier(); \
                   __builtin_amdgcn_sched_barrier(0); } while(0)

// ---------------------------------------------------------------------------
// adj fp32 [12000][12000] -> adjb bf16 [12000][K_PAD], zero-padded tail cols
// ---------------------------------------------------------------------------
__global__ __launch_bounds__(256) void k_convert(const float* __restrict__ adj,
                                                 short* __restrict__ adjb){
  const int r = blockIdx.x;
  const float* src = adj + (size_t)r * M_ROWS;
  short* dst = adjb + (size_t)r * K_PAD;
  for (int c0 = threadIdx.x * 4; c0 < K_PAD; c0 += 1024){
    s16x4 o;
    if (c0 < M_ROWS){
      f32x4 v = *(const f32x4*)(src + c0);
      #pragma unroll
      for (int j = 0; j < 4; ++j) o[j] = f2bf(v[j]);
    } else {
      o = (s16x4)0;
    }
    *(s16x4*)(dst + c0) = o;
  }
}

// ---------------------------------------------------------------------------
// zero HbT tail columns [12000..K_PAD)
// ---------------------------------------------------------------------------
__global__ __launch_bounds__(256) void k_zerotail(short* __restrict__ HbT){
  const int t = threadIdx.x;   // one thread per HbT row (256 rows)
  short* d = HbT + (size_t)t * K_PAD + M_ROWS;
  s16x8 z = (s16x8)0;
  #pragma unroll
  for (int i = 0; i < 4; ++i) *(s16x8*)(d + 8*i) = z;
}

// ---------------------------------------------------------------------------
// fp32 x [12000][256] -> bf16 HbT [256][K_PAD] (transposed)
// ---------------------------------------------------------------------------
__global__ __launch_bounds__(256) void k_transpose_bf16(const float* __restrict__ src,
                                                        short* __restrict__ dst){
  __shared__ float tile[32][257];
  const int t  = threadIdx.x;
  const int r0 = blockIdx.x * 32;
  {
    const int r = t >> 3, cs = (t & 7) * 32;
    const float* s = src + (size_t)(r0 + r) * FEAT + cs;
    #pragma unroll
    for (int i = 0; i < 8; ++i){
      f32x4 v = *(const f32x4*)(s + 4*i);
      tile[r][cs + 4*i + 0] = v[0];
      tile[r][cs + 4*i + 1] = v[1];
      tile[r][cs + 4*i + 2] = v[2];
      tile[r][cs + 4*i + 3] = v[3];
    }
  }
  __syncthreads();
  const int c = t;
  short* d = dst + (size_t)c * K_PAD + r0;
  #pragma unroll
  for (int i = 0; i < 4; ++i){
    s16x8 o;
    #pragma unroll
    for (int j = 0; j < 8; ++j) o[j] = f2bf(tile[8*i + j][c]);
    *(s16x8*)(d + 8*i) = o;
  }
}

// ---------------------------------------------------------------------------
// Big GEMM, m201-style 8-phase: P[s] = adjb[:, kslice] @ HbT^T[kslice, :]
// BM=256, BN=256, BK=64. 512 threads (8 waves, 2Mx4N), wave tile 128x64.
// LDS: 2 dbuf x {A-k0,A-k1,B-k0,B-k1} sub-blocks [256][32] bf16 = 128 KB.
// Per K-tile: 4 phases {ds_read subtile; stage 1 half-tile (2 gl16); barrier;
// setprio 16 MFMA; barrier}. vmcnt(4) at end of P1 and P3 only (never 0 in
// main loop). B-frags reused across the two m-half phases of each k-half.
// 2-way-free LDS slot swizzle via pre-swizzled global src + swizzled ds_read.
// ---------------------------------------------------------------------------
__global__ __launch_bounds__(512, 2) void k_gemm8p(const short* __restrict__ Abase,
                                                   const short* __restrict__ Bbase,
                                                   float* __restrict__ Pbase){
  __shared__ __align__(16) short lds[2][4][8192];  // [dbuf][A0,A1,B0,B1][256*32]

  const int t = threadIdx.x;
  const int w = t >> 6, l = t & 63;
  const int wm = w >> 2, wn = w & 3;
  const int lr = l & 15, lg = l >> 4;

  // bijective XCD-chunked swizzle of flat block id (235 = 8*29+3)
  int id = blockIdx.x;
  {
    const int xcd = id & 7, idx = id >> 3;
    id = (xcd < 3 ? xcd * 30 : 90 + (xcd - 3) * 29) + idx;
  }
  const int bm = id % 47, s = id / 47;
  const int row0 = bm * 256;
  const int u0  = (s < 3) ? s * 38 : 114 + (s - 3) * 37;  // units of 64
  const int nst = (s < 3) ? 38 : 37;

  // staging source offsets (pre-swizzled 16B slots within each row's 64B)
  size_t aoff[2], boff[2];
  #pragma unroll
  for (int j = 0; j < 2; ++j){
    const int i  = j * 512 + t;
    const int r  = i >> 2, sl = i & 3;
    const int sw = (r & 3) ^ ((r >> 2) & 3);
    int grow = row0 + r; if (grow > M_ROWS - 1) grow = M_ROWS - 1;
    aoff[j] = (size_t)grow * K_PAD + (size_t)((sl ^ sw) * 8);
    boff[j] = (size_t)r    * K_PAD + (size_t)((sl ^ sw) * 8);
  }

#define ST_AH(q, h, kelt) do{                                                   \
    gl16(Abase + aoff[0] + (size_t)(kelt), (char*)&lds[q][h][0] + w*1024);      \
    gl16(Abase + aoff[1] + (size_t)(kelt), (char*)&lds[q][h][0] + 8192 + w*1024); }while(0)
#define ST_BH(q, h, kelt) do{                                                   \
    gl16(Bbase + boff[0] + (size_t)(kelt), (char*)&lds[q][2+(h)][0] + w*1024);  \
    gl16(Bbase + boff[1] + (size_t)(kelt), (char*)&lds[q][2+(h)][0] + 8192 + w*1024); }while(0)

#define AF(q, h, mf) \
    (*(const s16x8*)&lds[q][h][ (wm*128 + (mf)*16 + lr) * 32 + \
      ((lg ^ ((wm*128 + (mf)*16 + lr) & 3) ^ (((wm*128 + (mf)*16 + lr) >> 2) & 3)) * 8) ])
#define BF(q, h, nf) \
    (*(const s16x8*)&lds[q][2+(h)][ (wn*64 + (nf)*16 + lr) * 32 + \
      ((lg ^ ((wn*64 + (nf)*16 + lr) & 3) ^ (((wn*64 + (nf)*16 + lr) >> 2) & 3)) * 8) ])

  f32x4 acc[8][4];
  #pragma unroll
  for (int m = 0; m < 8; ++m)
    #pragma unroll
    for (int n = 0; n < 4; ++n) acc[m][n] = (f32x4)(0.0f);

  // prologue: stage tile 0 (issue order Bk0, Ak0, Bk1, Ak1)
  {
    const int kb = u0 * 64;
    ST_BH(0, 0, kb); ST_AH(0, 0, kb);
    ST_BH(0, 1, kb + 32); ST_AH(0, 1, kb + 32);
  }
  VM4;    // Bk0 + Ak0 of tile 0 landed; k1 halves stay in flight
  BARR;

  for (int t2 = 0; t2 < nst; ++t2){
    const int q = t2 & 1, qn = q ^ 1;
    const bool stg = (t2 + 1 < nst);
    const int ke = (u0 + t2 + 1) * 64;

    s16x8 bfr[4], af[4];

    // ---- P0: k0, m0-3 (+B reads); stage B-k0(next) ----
    #pragma unroll
    for (int n = 0; n < 4; ++n) bfr[n] = BF(q, 0, n);
    #pragma unroll
    for (int m = 0; m < 4; ++m) af[m] = AF(q, 0, m);
    if (stg) ST_BH(qn, 0, ke);
    BARR;
    __builtin_amdgcn_s_setprio(1);
    #pragma unroll
    for (int m = 0; m < 4; ++m)
      #pragma unroll
      for (int n = 0; n < 4; ++n)
        acc[m][n] = mfma16(af[m], bfr[n], acc[m][n]);
    __builtin_amdgcn_s_setprio(0);
    BARR;

    // ---- P1: k0, m4-7 (B reused); stage A-k0(next) ----
    #pragma unroll
    for (int m = 0; m < 4; ++m) af[m] = AF(q, 0, m + 4);
    if (stg) ST_AH(qn, 0, ke);
    BARR;
    __builtin_amdgcn_s_setprio(1);
    #pragma unroll
    for (int m = 0; m < 4; ++m)
      #pragma unroll
      for (int n = 0; n < 4; ++n)
        acc[m + 4][n] = mfma16(af[m], bfr[n], acc[m + 4][n]);
    __builtin_amdgcn_s_setprio(0);
    if (stg) { VM4; } else { VM0; }   // tile t2's k1 halves landed
    BARR;

    // ---- P2: k1, m0-3 (+B reads); stage B-k1(next) ----
    #pragma unroll
    for (int n = 0; n < 4; ++n) bfr[n] = BF(q, 1, n);
    #pragma unroll
    for (int m = 0; m < 4; ++m) af[m] = AF(q, 1, m);
    if (stg) ST_BH(qn, 1, ke + 32);
    BARR;
    __builtin_amdgcn_s_setprio(1);
    #pragma unroll
    for (int m = 0; m < 4; ++m)
      #pragma unroll
      for (int n = 0; n < 4; ++n)
        acc[m][n] = mfma16(af[m], bfr[n], acc[m][n]);
    __builtin_amdgcn_s_setprio(0);
    BARR;

    // ---- P3: k1, m4-7 (B reused); stage A-k1(next) ----
    #pragma unroll
    for (int m = 0; m < 4; ++m) af[m] = AF(q, 1, m + 4);
    if (stg) ST_AH(qn, 1, ke + 32);
    BARR;
    __builtin_amdgcn_s_setprio(1);
    #pragma unroll
    for (int m = 0; m < 4; ++m)
      #pragma unroll
      for (int n = 0; n < 4; ++n)
        acc[m + 4][n] = mfma16(af[m], bfr[n], acc[m + 4][n]);
    __builtin_amdgcn_s_setprio(0);
    if (stg) { VM4; }                 // next tile's k0 halves landed
    BARR;
  }
#undef ST_AH
#undef ST_BH
#undef AF
#undef BF

  // epilogue: C/D layout col=lane&15, row=(lane>>4)*4+reg
  float* P = Pbase + (size_t)s * PSLAB;
  #pragma unroll
  for (int m = 0; m < 8; ++m){
    const int row = row0 + wm*128 + m*16 + lg*4;
    #pragma unroll
    for (int n = 0; n < 4; ++n){
      const int col = wn*64 + n*16 + lr;
      float* pp = P + (size_t)row * FEAT + col;
      #pragma unroll
      for (int r = 0; r < 4; ++r)
        if (row + r < M_ROWS) pp[(size_t)r * FEAT] = acc[m][n][r];
    }
  }
}

// ---------------------------------------------------------------------------
// HbT = transpose(l2norm_rows(relu((sum_s P[s]) @ W + b))) as bf16 [256][K_PAD]
// ---------------------------------------------------------------------------
__global__ __launch_bounds__(256) void k_fused2(const float* __restrict__ Pbase,
                                                const float* __restrict__ W,
                                                const float* __restrict__ b,
                                                short* __restrict__ HbT){
  __shared__ float ylds[32][257];
  __shared__ float red[32][33];
  __shared__ float scale[32];
  const int t  = threadIdx.x;
  const int r0 = blockIdx.x * 32;
  {
    const int r = t >> 3, cs = (t & 7) * 32;
    const size_t off = (size_t)(r0 + r) * FEAT + cs;
    f32x4 a4[8];
    #pragma unroll
    for (int i = 0; i < 8; ++i) a4[i] = *(const f32x4*)(Pbase + off + 4*i);
    #pragma unroll
    for (int s = 1; s < NSLICE; ++s){
      const float* ps = Pbase + (size_t)s * PSLAB + off;
      #pragma unroll
      for (int i = 0; i < 8; ++i) a4[i] += *(const f32x4*)(ps + 4*i);
    }
    #pragma unroll
    for (int i = 0; i < 8; ++i){
      ylds[r][cs + 4*i + 0] = a4[i][0];
      ylds[r][cs + 4*i + 1] = a4[i][1];
      ylds[r][cs + 4*i + 2] = a4[i][2];
      ylds[r][cs + 4*i + 3] = a4[i][3];
    }
  }
  __syncthreads();

  const int rg = t >> 5;   // rows rg*4 .. rg*4+3
  const int cg = t & 31;   // cols cg*8 .. cg*8+7
  float acc[4][8];
  {
    float bias[8];
    #pragma unroll
    for (int j = 0; j < 8; ++j) bias[j] = b[cg*8 + j];
    #pragma unroll
    for (int i = 0; i < 4; ++i)
      #pragma unroll
      for (int j = 0; j < 8; ++j) acc[i][j] = bias[j];
  }

  #pragma unroll 4
  for (int k = 0; k < FEAT; ++k){
    float yv[4];
    #pragma unroll
    for (int i = 0; i < 4; ++i) yv[i] = ylds[rg*4 + i][k];
    f32x4 w0 = *(const f32x4*)(W + (size_t)k * FEAT + cg*8);
    f32x4 w1 = *(const f32x4*)(W + (size_t)k * FEAT + cg*8 + 4);
    #pragma unroll
    for (int i = 0; i < 4; ++i){
      #pragma unroll
      for (int j = 0; j < 4; ++j){
        acc[i][j]     += yv[i] * w0[j];
        acc[i][4 + j] += yv[i] * w1[j];
      }
    }
  }

  #pragma unroll
  for (int i = 0; i < 4; ++i){
    float ss = 0.0f;
    #pragma unroll
    for (int j = 0; j < 8; ++j){
      float v = fmaxf(acc[i][j], 0.0f);
      acc[i][j] = v;
      ss += v * v;
    }
    red[rg*4 + i][cg] = ss;
  }
  __syncthreads();
  if (t < 32){
    float ssum = 0.0f;
    #pragma unroll
    for (int j = 0; j < 32; ++j) ssum += red[t][j];
    scale[t] = 1.0f / fmaxf(sqrtf(ssum), 1e-12f);
  }
  __syncthreads();

  float sc[4];
  #pragma unroll
  for (int i = 0; i < 4; ++i) sc[i] = scale[rg*4 + i];
  #pragma unroll
  for (int j = 0; j < 8; ++j){
    s16x4 o;
    #pragma unroll
    for (int i = 0; i < 4; ++i) o[i] = f2bf(acc[i][j] * sc[i]);
    *(s16x4*)(HbT + (size_t)(cg*8 + j) * K_PAD + r0 + rg*4) = o;
  }
}

// ---------------------------------------------------------------------------
// out = (sum_s P[s]) @ W2 + b2    (12000 x 40)
// ---------------------------------------------------------------------------
__global__ __launch_bounds__(256) void k_final2(const float* __restrict__ Pbase,
                                                const float* __restrict__ W2,
                                                const float* __restrict__ b2,
                                                float* __restrict__ out){
  __shared__ float ylds[32][257];
  const int t  = threadIdx.x;
  const int r0 = blockIdx.x * 32;
  {
    const int r = t >> 3, cs = (t & 7) * 32;
    const size_t off = (size_t)(r0 + r) * FEAT + cs;
    f32x4 a4[8];
    #pragma unroll
    for (int i = 0; i < 8; ++i) a4[i] = *(const f32x4*)(Pbase + off + 4*i);
    #pragma unroll
    for (int s = 1; s < NSLICE; ++s){
      const float* ps = Pbase + (size_t)s * PSLAB + off;
      #pragma unroll
      for (int i = 0; i < 8; ++i) a4[i] += *(const f32x4*)(ps + 4*i);
    }
    #pragma unroll
    for (int i = 0; i < 8; ++i){
      ylds[r][cs + 4*i + 0] = a4[i][0];
      ylds[r][cs + 4*i + 1] = a4[i][1];
      ylds[r][cs + 4*i + 2] = a4[i][2];
      ylds[r][cs + 4*i + 3] = a4[i][3];
    }
  }
  __syncthreads();

  #pragma unroll
  for (int e = t; e < 32 * NCLS; e += 256){
    const int r = e / NCLS, n = e % NCLS;
    float a = b2[n];
    #pragma unroll 8
    for (int k = 0; k < FEAT; ++k)
      a = fmaf(ylds[r][k], W2[(size_t)k * NCLS + n], a);
    out[(size_t)(r0 + r) * NCLS + n] = a;
  }
}

// ---------------------------------------------------------------------------
extern "C" void kernel_launch(void* const* d_in, const int* in_sizes, int n_in,
                              void* d_out, int out_size, void* d_ws, size_t ws_size,
                              hipStream_t stream){
  const float* adj = (const float*)d_in[0];
  const float* x   = (const float*)d_in[1];
  const float* W0  = (const float*)d_in[2];
  const float* b0  = (const float*)d_in[3];
  const float* W1  = (const float*)d_in[4];
  const float* b1  = (const float*)d_in[5];
  const float* W2  = (const float*)d_in[6];
  const float* b2  = (const float*)d_in[7];
  float* out = (float*)d_out;

  char* ws = (char*)d_ws;
  const size_t HBT_BYTES  = (size_t)FEAT * K_PAD * 2;      //   6,160,384
  const size_t ADJB_BYTES = (size_t)M_ROWS * K_PAD * 2;    // 288,768,000

  short* HbT  = (short*)ws;
  short* adjb = (short*)(ws + HBT_BYTES);
  float* P    = (float*)(ws + HBT_BYTES + ADJB_BYTES);

  const dim3 b256(256), b512(512);

  k_convert<<<M_ROWS, b256, 0, stream>>>(adj, adjb);
  k_zerotail<<<1, b256, 0, stream>>>(HbT);
  k_transpose_bf16<<<375, b256, 0, stream>>>(x, HbT);

  // layer 0
  k_gemm8p<<<47 * NSLICE, b512, 0, stream>>>(adjb, HbT, P);
  k_fused2<<<375, b256, 0, stream>>>(P, W0, b0, HbT);
  // layer 1
  k_gemm8p<<<47 * NSLICE, b512, 0, stream>>>(adjb, HbT, P);
  k_fused2<<<375, b256, 0, stream>>>(P, W1, b1, HbT);
  // layer 2
  k_gemm8p<<<47 * NSLICE, b512, 0, stream>>>(adjb, HbT, P);
  k_final2<<<375, b256, 0, stream>>>(P, W2, b2, out);
}

// Round 6
// 558.946 us; speedup vs baseline: 1.5287x; 1.0287x over previous
//
#include <hip/hip_runtime.h>
#include <hip/hip_bf16.h>

#define M_ROWS 12000
#define K_PAD  12032          // 188 * 64
#define FEAT   256
#define NCLS   40
#define NSLICE 5
#define NTILES 188            // K-tiles of 64
#define NBM    47             // M-tiles of 256
#define PSLAB  (M_ROWS * FEAT)         // floats per P slab
#define TILE_SHORTS 16384              // 32 KB tile image
#define HALF_SHORTS 8192

typedef __attribute__((ext_vector_type(4))) float f32x4;
typedef __attribute__((ext_vector_type(8))) short s16x8;
typedef __attribute__((ext_vector_type(4))) short s16x4;
typedef unsigned int u32;

__device__ __forceinline__ short f2bf(float f){
  __hip_bfloat16 h = __float2bfloat16(f);
  union { __hip_bfloat16 h; short s; } u; u.h = h; return u.s;
}

__device__ __forceinline__ f32x4 mfma16(s16x8 a, s16x8 b, f32x4 c){
  return __builtin_amdgcn_mfma_f32_16x16x32_bf16(a, b, c, 0, 0, 0);
}

__device__ __forceinline__ void gl16(const void* g, void* l){
  __builtin_amdgcn_global_load_lds(
      (const __attribute__((address_space(1))) u32*)g,
      (__attribute__((address_space(3))) u32*)l, 16, 0, 0);
}

#define VM4   do { asm volatile("s_waitcnt vmcnt(4)" ::: "memory"); \
                   __builtin_amdgcn_sched_barrier(0); } while(0)
#define VM0   do { asm volatile("s_waitcnt vmcnt(0)" ::: "memory"); \
                   __builtin_amdgcn_sched_barrier(0); } while(0)
#define BARR  do { __builtin_amdgcn_s_barrier(); \
                   __builtin_amdgcn_sched_barrier(0); } while(0)

__device__ __forceinline__ int swz(int r){ return (r & 3) ^ ((r >> 2) & 3); }

// ---------------------------------------------------------------------------
// Pack adj fp32 into per-(bm,tile) 32 KB bf16 LDS images, swizzle baked in.
// image[h][r][sl][e] = bf16(adj[bm*256+r][tile*64 + h*32 + ((sl^swz(r))*8)+e])
// (rows clamped; cols >= 12000 zero-filled)
// ---------------------------------------------------------------------------
__global__ __launch_bounds__(256) void k_pack(const float* __restrict__ adj,
                                              short* __restrict__ Apack){
  const int tile = blockIdx.x;   // 0..187
  const int bm   = blockIdx.y;   // 0..46
  short* dst = Apack + ((size_t)bm * NTILES + tile) * TILE_SHORTS;
  const int t = threadIdx.x;
  #pragma unroll
  for (int v = 0; v < 8; ++v){
    const int si = v * 256 + t;        // 16B slot index 0..2047
    const int h  = si >> 10;
    const int rm = si & 1023;
    const int r  = rm >> 2, sl = rm & 3;
    int grow = bm * 256 + r; if (grow > M_ROWS - 1) grow = M_ROWS - 1;
    const int c0 = tile * 64 + h * 32 + ((sl ^ swz(r)) * 8);
    s16x8 o;
    if (c0 < M_ROWS){
      const float* sp = adj + (size_t)grow * M_ROWS + c0;
      f32x4 f0 = *(const f32x4*)(sp);
      f32x4 f1 = *(const f32x4*)(sp + 4);
      #pragma unroll
      for (int j = 0; j < 4; ++j){ o[j] = f2bf(f0[j]); o[4+j] = f2bf(f1[j]); }
    } else {
      o = (s16x8)0;
    }
    *(s16x8*)(dst + (size_t)si * 8) = o;
  }
}

// ---------------------------------------------------------------------------
// fp32 x [12000][256] -> Bpack tile images (transposed, swizzle baked in).
// Block 375 instead zeroes the k-pad region (tile 187, h=1).
// ---------------------------------------------------------------------------
__global__ __launch_bounds__(256) void k_transpose_pack(const float* __restrict__ src,
                                                        short* __restrict__ Bpack){
  const int t = threadIdx.x;
  if (blockIdx.x == 375){   // zero pad: k in [12000,12032)
    short* d = Bpack + (size_t)187 * TILE_SHORTS + HALF_SHORTS + t * 32;
    s16x8 z = (s16x8)0;
    #pragma unroll
    for (int i = 0; i < 4; ++i) *(s16x8*)(d + 8*i) = z;
    return;
  }
  __shared__ float tile[32][257];
  const int r0 = blockIdx.x * 32;     // k-base
  {
    const int r = t >> 3, cs = (t & 7) * 32;
    const float* s = src + (size_t)(r0 + r) * FEAT + cs;
    #pragma unroll
    for (int i = 0; i < 8; ++i){
      f32x4 v = *(const f32x4*)(s + 4*i);
      tile[r][cs + 4*i + 0] = v[0];
      tile[r][cs + 4*i + 1] = v[1];
      tile[r][cs + 4*i + 2] = v[2];
      tile[r][cs + 4*i + 3] = v[3];
    }
  }
  __syncthreads();
  const int c = t;                    // output column 0..255
  const int kt = r0 >> 6, hh = (r0 >> 5) & 1, sc = swz(c);
  short* d = Bpack + (size_t)kt * TILE_SHORTS + hh * HALF_SHORTS + c * 32;
  #pragma unroll
  for (int i = 0; i < 4; ++i){        // k group r0+8i..+7
    s16x8 o;
    #pragma unroll
    for (int j = 0; j < 8; ++j) o[j] = f2bf(tile[8*i + j][c]);
    *(s16x8*)(d + ((i ^ sc) * 8)) = o;
  }
}

// ---------------------------------------------------------------------------
// Big GEMM, 8-phase (unchanged schedule from r5); sources are packed images:
// every gl16 reads contiguous [base + tile*32KB + h*16KB + j*8KB + t*16].
// ---------------------------------------------------------------------------
__global__ __launch_bounds__(512, 2) void k_gemm8p(const short* __restrict__ Apack,
                                                   const short* __restrict__ Bpack,
                                                   float* __restrict__ Pbase){
  __shared__ __align__(16) short lds[2][4][8192];  // [dbuf][A0,A1,B0,B1]

  const int t = threadIdx.x;
  const int w = t >> 6, l = t & 63;
  const int wm = w >> 2, wn = w & 3;
  const int lr = l & 15, lg = l >> 4;

  // bijective XCD-chunked swizzle of flat block id (235 = 8*29+3)
  int id = blockIdx.x;
  {
    const int xcd = id & 7, idx = id >> 3;
    id = (xcd < 3 ? xcd * 30 : 90 + (xcd - 3) * 29) + idx;
  }
  const int bm = id % NBM, s = id / NBM;
  const int row0 = bm * 256;
  const int u0  = (s < 3) ? s * 38 : 114 + (s - 3) * 37;  // tile index
  const int nst = (s < 3) ? 38 : 37;

  const char* Ab = (const char*)(Apack + (size_t)bm * NTILES * TILE_SHORTS);
  const char* Bb = (const char*)Bpack;
  const size_t tp = (size_t)t * 16;   // per-lane source offset within half-image

#define ST_AH(q, h, kt) do{                                                   \
    const char* s_ = Ab + (size_t)(kt) * 32768 + (h) * 16384 + tp;            \
    gl16(s_,        (char*)&lds[q][h][0] + w*1024);                           \
    gl16(s_ + 8192, (char*)&lds[q][h][0] + 8192 + w*1024); }while(0)
#define ST_BH(q, h, kt) do{                                                   \
    const char* s_ = Bb + (size_t)(kt) * 32768 + (h) * 16384 + tp;            \
    gl16(s_,        (char*)&lds[q][2+(h)][0] + w*1024);                       \
    gl16(s_ + 8192, (char*)&lds[q][2+(h)][0] + 8192 + w*1024); }while(0)

#define AF(q, h, mf) \
    (*(const s16x8*)&lds[q][h][ (wm*128 + (mf)*16 + lr) * 32 + \
      ((lg ^ swz(wm*128 + (mf)*16 + lr)) * 8) ])
#define BF(q, h, nf) \
    (*(const s16x8*)&lds[q][2+(h)][ (wn*64 + (nf)*16 + lr) * 32 + \
      ((lg ^ swz(wn*64 + (nf)*16 + lr)) * 8) ])

  f32x4 acc[8][4];
  #pragma unroll
  for (int m = 0; m < 8; ++m)
    #pragma unroll
    for (int n = 0; n < 4; ++n) acc[m][n] = (f32x4)(0.0f);

  // prologue: stage tile 0 (order Bk0, Ak0, Bk1, Ak1)
  ST_BH(0, 0, u0); ST_AH(0, 0, u0);
  ST_BH(0, 1, u0); ST_AH(0, 1, u0);
  VM4;    // Bk0+Ak0 landed; k1 halves stay in flight
  BARR;

  for (int t2 = 0; t2 < nst; ++t2){
    const int q = t2 & 1, qn = q ^ 1;
    const bool stg = (t2 + 1 < nst);
    const int ktn = u0 + t2 + 1;

    s16x8 bfr[4], af[4];

    // ---- P0: k0, m0-3 (+B reads); stage B-k0(next) ----
    #pragma unroll
    for (int n = 0; n < 4; ++n) bfr[n] = BF(q, 0, n);
    #pragma unroll
    for (int m = 0; m < 4; ++m) af[m] = AF(q, 0, m);
    if (stg) ST_BH(qn, 0, ktn);
    BARR;
    __builtin_amdgcn_s_setprio(1);
    #pragma unroll
    for (int m = 0; m < 4; ++m)
      #pragma unroll
      for (int n = 0; n < 4; ++n)
        acc[m][n] = mfma16(af[m], bfr[n], acc[m][n]);
    __builtin_amdgcn_s_setprio(0);
    BARR;

    // ---- P1: k0, m4-7 (B reused); stage A-k0(next) ----
    #pragma unroll
    for (int m = 0; m < 4; ++m) af[m] = AF(q, 0, m + 4);
    if (stg) ST_AH(qn, 0, ktn);
    BARR;
    __builtin_amdgcn_s_setprio(1);
    #pragma unroll
    for (int m = 0; m < 4; ++m)
      #pragma unroll
      for (int n = 0; n < 4; ++n)
        acc[m + 4][n] = mfma16(af[m], bfr[n], acc[m + 4][n]);
    __builtin_amdgcn_s_setprio(0);
    if (stg) { VM4; } else { VM0; }   // this tile's k1 halves landed
    BARR;

    // ---- P2: k1, m0-3 (+B reads); stage B-k1(next) ----
    #pragma unroll
    for (int n = 0; n < 4; ++n) bfr[n] = BF(q, 1, n);
    #pragma unroll
    for (int m = 0; m < 4; ++m) af[m] = AF(q, 1, m);
    if (stg) ST_BH(qn, 1, ktn);
    BARR;
    __builtin_amdgcn_s_setprio(1);
    #pragma unroll
    for (int m = 0; m < 4; ++m)
      #pragma unroll
      for (int n = 0; n < 4; ++n)
        acc[m][n] = mfma16(af[m], bfr[n], acc[m][n]);
    __builtin_amdgcn_s_setprio(0);
    BARR;

    // ---- P3: k1, m4-7 (B reused); stage A-k1(next) ----
    #pragma unroll
    for (int m = 0; m < 4; ++m) af[m] = AF(q, 1, m + 4);
    if (stg) ST_AH(qn, 1, ktn);
    BARR;
    __builtin_amdgcn_s_setprio(1);
    #pragma unroll
    for (int m = 0; m < 4; ++m)
      #pragma unroll
      for (int n = 0; n < 4; ++n)
        acc[m + 4][n] = mfma16(af[m], bfr[n], acc[m + 4][n]);
    __builtin_amdgcn_s_setprio(0);
    if (stg) { VM4; }                 // next tile's k0 halves landed
    BARR;
  }
#undef ST_AH
#undef ST_BH
#undef AF
#undef BF

  // epilogue: C/D layout col=lane&15, row=(lane>>4)*4+reg
  float* P = Pbase + (size_t)s * PSLAB;
  #pragma unroll
  for (int m = 0; m < 8; ++m){
    const int row = row0 + wm*128 + m*16 + lg*4;
    #pragma unroll
    for (int n = 0; n < 4; ++n){
      const int col = wn*64 + n*16 + lr;
      float* pp = P + (size_t)row * FEAT + col;
      #pragma unroll
      for (int r = 0; r < 4; ++r)
        if (row + r < M_ROWS) pp[(size_t)r * FEAT] = acc[m][n][r];
    }
  }
}

// ---------------------------------------------------------------------------
// Bpack = pack(transpose(l2norm_rows(relu((sum_s P[s]) @ W + b))))
// ---------------------------------------------------------------------------
__global__ __launch_bounds__(256) void k_fused2(const float* __restrict__ Pbase,
                                                const float* __restrict__ W,
                                                const float* __restrict__ b,
                                                short* __restrict__ Bpack){
  __shared__ float ylds[32][257];
  __shared__ float red[32][33];
  __shared__ float scale[32];
  const int t  = threadIdx.x;
  const int r0 = blockIdx.x * 32;     // output k-base (H row block)
  {
    const int r = t >> 3, cs = (t & 7) * 32;
    const size_t off = (size_t)(r0 + r) * FEAT + cs;
    f32x4 a4[8];
    #pragma unroll
    for (int i = 0; i < 8; ++i) a4[i] = *(const f32x4*)(Pbase + off + 4*i);
    #pragma unroll
    for (int s = 1; s < NSLICE; ++s){
      const float* ps = Pbase + (size_t)s * PSLAB + off;
      #pragma unroll
      for (int i = 0; i < 8; ++i) a4[i] += *(const f32x4*)(ps + 4*i);
    }
    #pragma unroll
    for (int i = 0; i < 8; ++i){
      ylds[r][cs + 4*i + 0] = a4[i][0];
      ylds[r][cs + 4*i + 1] = a4[i][1];
      ylds[r][cs + 4*i + 2] = a4[i][2];
      ylds[r][cs + 4*i + 3] = a4[i][3];
    }
  }
  __syncthreads();

  const int rg = t >> 5;   // row group rg*4..+3 (k within block)
  const int cg = t & 31;   // col group cg*8..+7
  float acc[4][8];
  {
    float bias[8];
    #pragma unroll
    for (int j = 0; j < 8; ++j) bias[j] = b[cg*8 + j];
    #pragma unroll
    for (int i = 0; i < 4; ++i)
      #pragma unroll
      for (int j = 0; j < 8; ++j) acc[i][j] = bias[j];
  }

  #pragma unroll 4
  for (int k = 0; k < FEAT; ++k){
    float yv[4];
    #pragma unroll
    for (int i = 0; i < 4; ++i) yv[i] = ylds[rg*4 + i][k];
    f32x4 w0 = *(const f32x4*)(W + (size_t)k * FEAT + cg*8);
    f32x4 w1 = *(const f32x4*)(W + (size_t)k * FEAT + cg*8 + 4);
    #pragma unroll
    for (int i = 0; i < 4; ++i){
      #pragma unroll
      for (int j = 0; j < 4; ++j){
        acc[i][j]     += yv[i] * w0[j];
        acc[i][4 + j] += yv[i] * w1[j];
      }
    }
  }

  #pragma unroll
  for (int i = 0; i < 4; ++i){
    float ss = 0.0f;
    #pragma unroll
    for (int j = 0; j < 8; ++j){
      float v = fmaxf(acc[i][j], 0.0f);
      acc[i][j] = v;
      ss += v * v;
    }
    red[rg*4 + i][cg] = ss;
  }
  __syncthreads();
  if (t < 32){
    float ssum = 0.0f;
    #pragma unroll
    for (int j = 0; j < 32; ++j) ssum += red[t][j];
    scale[t] = 1.0f / fmaxf(sqrtf(ssum), 1e-12f);
  }
  __syncthreads();

  float sc[4];
  #pragma unroll
  for (int i = 0; i < 4; ++i) sc[i] = scale[rg*4 + i];

  // packed write: k = r0 + rg*4 + i, column c = cg*8 + j
  const int kb   = r0 + rg * 4;
  const int kt   = kb >> 6, hh = (kb >> 5) & 1, g = (kb >> 3) & 3, e0 = kb & 7;
  short* dbase = Bpack + (size_t)kt * TILE_SHORTS + hh * HALF_SHORTS;
  #pragma unroll
  for (int j = 0; j < 8; ++j){
    const int c = cg * 8 + j;
    s16x4 o;
    #pragma unroll
    for (int i = 0; i < 4; ++i) o[i] = f2bf(acc[i][j] * sc[i]);
    *(s16x4*)(dbase + c * 32 + ((g ^ swz(c)) * 8) + e0) = o;
  }
}

// ---------------------------------------------------------------------------
// out = (sum_s P[s]) @ W2 + b2    (12000 x 40)
// ---------------------------------------------------------------------------
__global__ __launch_bounds__(256) void k_final2(const float* __restrict__ Pbase,
                                                const float* __restrict__ W2,
                                                const float* __restrict__ b2,
                                                float* __restrict__ out){
  __shared__ float ylds[32][257];
  const int t  = threadIdx.x;
  const int r0 = blockIdx.x * 32;
  {
    const int r = t >> 3, cs = (t & 7) * 32;
    const size_t off = (size_t)(r0 + r) * FEAT + cs;
    f32x4 a4[8];
    #pragma unroll
    for (int i = 0; i < 8; ++i) a4[i] = *(const f32x4*)(Pbase + off + 4*i);
    #pragma unroll
    for (int s = 1; s < NSLICE; ++s){
      const float* ps = Pbase + (size_t)s * PSLAB + off;
      #pragma unroll
      for (int i = 0; i < 8; ++i) a4[i] += *(const f32x4*)(ps + 4*i);
    }
    #pragma unroll
    for (int i = 0; i < 8; ++i){
      ylds[r][cs + 4*i + 0] = a4[i][0];
      ylds[r][cs + 4*i + 1] = a4[i][1];
      ylds[r][cs + 4*i + 2] = a4[i][2];
      ylds[r][cs + 4*i + 3] = a4[i][3];
    }
  }
  __syncthreads();

  #pragma unroll
  for (int e = t; e < 32 * NCLS; e += 256){
    const int r = e / NCLS, n = e % NCLS;
    float a = b2[n];
    #pragma unroll 8
    for (int k = 0; k < FEAT; ++k)
      a = fmaf(ylds[r][k], W2[(size_t)k * NCLS + n], a);
    out[(size_t)(r0 + r) * NCLS + n] = a;
  }
}

// ---------------------------------------------------------------------------
extern "C" void kernel_launch(void* const* d_in, const int* in_sizes, int n_in,
                              void* d_out, int out_size, void* d_ws, size_t ws_size,
                              hipStream_t stream){
  const float* adj = (const float*)d_in[0];
  const float* x   = (const float*)d_in[1];
  const float* W0  = (const float*)d_in[2];
  const float* b0  = (const float*)d_in[3];
  const float* W1  = (const float*)d_in[4];
  const float* b1  = (const float*)d_in[5];
  const float* W2  = (const float*)d_in[6];
  const float* b2  = (const float*)d_in[7];
  float* out = (float*)d_out;

  char* ws = (char*)d_ws;
  const size_t BPACK_BYTES = (size_t)NTILES * TILE_SHORTS * 2;          //   6,160,384
  const size_t APACK_BYTES = (size_t)NBM * NTILES * TILE_SHORTS * 2;    // 289,538,048

  short* Bpack = (short*)ws;
  short* Apack = (short*)(ws + BPACK_BYTES);
  float* P     = (float*)(ws + BPACK_BYTES + APACK_BYTES);

  const dim3 b256(256), b512(512);

  k_pack<<<dim3(NTILES, NBM), b256, 0, stream>>>(adj, Apack);
  k_transpose_pack<<<376, b256, 0, stream>>>(x, Bpack);

  // layer 0
  k_gemm8p<<<NBM * NSLICE, b512, 0, stream>>>(Apack, Bpack, P);
  k_fused2<<<375, b256, 0, stream>>>(P, W0, b0, Bpack);
  // layer 1
  k_gemm8p<<<NBM * NSLICE, b512, 0, stream>>>(Apack, Bpack, P);
  k_fused2<<<375, b256, 0, stream>>>(P, W1, b1, Bpack);
  // layer 2
  k_gemm8p<<<NBM * NSLICE, b512, 0, stream>>>(Apack, Bpack, P);
  k_final2<<<375, b256, 0, stream>>>(P, W2, b2, out);
}